// Round 12
// baseline (201.630 us; speedup 1.0000x reference)
//
#include <hip/hip_runtime.h>
#include <math.h>

static constexpr int  Bb = 8;
static constexpr int  L  = 2048;
static constexpr int  H  = 256;
static constexpr long BL = (long)Bb * L;     // 16384
static constexpr long LH = (long)L * H;      // 524288
static constexpr long LL = (long)L * L;      // 4194304
static constexpr int  NCH = 16;              // i-chunks (128 each) for stats

typedef __attribute__((ext_vector_type(8))) unsigned short u16x8;
typedef __attribute__((ext_vector_type(4))) unsigned short u16x4;
typedef __attribute__((ext_vector_type(8))) _Float16       f16x8;
typedef __attribute__((ext_vector_type(4))) float          f32x4;

__device__ __forceinline__ unsigned short f2hu(float x) {
    union { _Float16 h; unsigned short u; } v; v.h = (_Float16)x; return v.u;
}
__device__ __forceinline__ float hu2f(unsigned short u) {
    union { unsigned short u; _Float16 h; } v; v.u = u; return (float)v.h;
}
__device__ __forceinline__ void gl_lds16(const unsigned short* g, unsigned short* l) {
    __builtin_amdgcn_global_load_lds(
        (const __attribute__((address_space(1))) unsigned int*)g,
        (__attribute__((address_space(3))) unsigned int*)l, 16, 0, 0);
}

// ---------------------------------------------------------------------------
// convert fp32 -> fp16
// ---------------------------------------------------------------------------
__global__ __launch_bounds__(256)
void cvt_g(const float* __restrict__ x, unsigned short* __restrict__ h)
{
    const long i = ((long)blockIdx.x * 256 + threadIdx.x) * 4;
    float4 v = *(const float4*)(x + i);
    u16x4 o;
    o[0] = f2hu(v.x); o[1] = f2hu(v.y); o[2] = f2hu(v.z); o[3] = f2hu(v.w);
    *(u16x4*)(h + i) = o;
}

// WP (blocks [0,64)) + W_out (blocks [64,256)) in one launch
__global__ __launch_bounds__(256)
void cvt_two(const float* __restrict__ x1, unsigned short* __restrict__ h1,
             const float* __restrict__ x2, unsigned short* __restrict__ h2)
{
    const float* x; unsigned short* hp; long base;
    if (blockIdx.x < 64) { x = x1; hp = h1; base = (long)blockIdx.x * 1024; }
    else { x = x2; hp = h2; base = (long)(blockIdx.x - 64) * 1024; }
    const long i = base + (long)threadIdx.x * 4;
    float4 v = *(const float4*)(x + i);
    u16x4 o;
    o[0] = f2hu(v.x); o[1] = f2hu(v.y); o[2] = f2hu(v.z); o[3] = f2hu(v.w);
    *(u16x4*)(hp + i) = o;
}

// ---------------------------------------------------------------------------
// transpose g -> gT in MFMA B-fragment tiled layout:
// gTf[b][h/16][j/32][lane][8] ; elem e at j = (e>>2)*16 + (lane>>4)*4 + (e&3)
// ---------------------------------------------------------------------------
__global__ __launch_bounds__(256)
void transpose_h16(const unsigned short* __restrict__ in, unsigned short* __restrict__ outf)
{
    __shared__ unsigned short T[32][33];
    const int b = blockIdx.z, j0 = blockIdx.x * 32, h0 = blockIdx.y * 32;
    const int t = threadIdx.x, r = t >> 3, c4 = (t & 7) << 2;
    const unsigned short* inb = in + (long)b * LH;
    unsigned short* ob = outf + (long)b * LH;
    u16x4 v = *(const u16x4*)(inb + (long)(j0 + r) * H + h0 + c4);
#pragma unroll
    for (int e = 0; e < 4; ++e) T[r][c4 + e] = v[e];
    __syncthreads();
    const int f = t >> 7, lam = (t & 127) >> 1, half = t & 1;
    const int hloc  = f * 16 + (lam & 15);
    const int jbase = half * 16 + (lam >> 4) * 4;
    u16x4 o;
#pragma unroll
    for (int d = 0; d < 4; ++d) o[d] = T[jbase + d][hloc];
    *(u16x4*)(ob + ((long)((h0 >> 4) + f) * (L / 32) + (j0 >> 5)) * 512
                 + lam * 8 + half * 4) = o;
}

// ---------------------------------------------------------------------------
// combine per-chunk stats -> fp16 rescale factors r16[b][c][j] = exp(m_c-m)*zi
// ---------------------------------------------------------------------------
__global__ __launch_bounds__(256)
void col_stats_r(const float* __restrict__ pm, const float* __restrict__ pz,
                 unsigned short* __restrict__ r16)
{
    const long idx = (long)blockIdx.x * 256 + threadIdx.x;   // b*L + j
    const long b = idx / L, j = idx - b * L;
    const float* pmb = pm + b * (long)NCH * L + j;
    const float* pzb = pz + b * (long)NCH * L + j;
    float m = -1e30f;
#pragma unroll
    for (int c = 0; c < NCH; ++c) m = fmaxf(m, pmb[(long)c * L]);
    float z = 0.f;
#pragma unroll
    for (int c = 0; c < NCH; ++c) z += pzb[(long)c * L] * __expf(pmb[(long)c * L] - m);
    const float zi = 1.f / z;
    unsigned short* rb = r16 + b * (long)NCH * L + j;
#pragma unroll
    for (int c = 0; c < NCH; ++c) rb[(long)c * L] = f2hu(__expf(pmb[(long)c * L] - m) * zi);
}

// ---------------------------------------------------------------------------
// Unified NT MFMA GEMM (fp16 inputs), 128x128 tile, NSEG segments of K=256, BK=32.
// MODE 0 (K2, swapped: A=g rows j, B=Wh rows i => computes S^T tiles):
//   row(j)-stats per i-chunk + P' = fp16(exp(s - m_chunk)) in A-frag tiled
//   layout [i/16][j/16][lane][4]. No epilogue LDS bounce. global_load_lds.
// MODE 2: fp16 C write (K1: Wh).                              global_load_lds.
// MODE 1: seg2 A synthesized fp16(A0*A1), bias+relu (K5).     reg-staged.
// ---------------------------------------------------------------------------
template<int MODE, int NSEG>
__global__ __launch_bounds__(256)
void mfma_nt(const unsigned short* A0, const unsigned short* A1, const unsigned short* A2,
             const unsigned short* B0, const unsigned short* B1, const unsigned short* B2,
             float* __restrict__ C, unsigned short* __restrict__ Ch,
             float* __restrict__ pm, float* __restrict__ pz,
             const float* __restrict__ bias,
             int N, int lda, int ldb,
             long strideA, long strideB, long strideC)
{
    __shared__ __align__(16) unsigned short As[128][32];
    __shared__ __align__(16) unsigned short Bs[128][32];
    __shared__ float smx[2][128];
    __shared__ float szx[2][128];
    __shared__ float colm[128];
    const int tid  = threadIdx.x;
    const int wid  = tid >> 6, lane = tid & 63;
    const int wm   = wid >> 1, wn = wid & 1;
    const long b   = blockIdx.z;
    const int m0   = blockIdx.x * 128, n0 = blockIdx.y * 128;
    const int lrow = tid >> 2, lkc = (tid & 3) << 3;
    const int frow = lane & 15, fk = (lane >> 4) << 3;
    f32x4 acc[4][4];
#pragma unroll
    for (int i = 0; i < 4; ++i)
#pragma unroll
        for (int j = 0; j < 4; ++j) acc[i][j] = (f32x4){0.f, 0.f, 0.f, 0.f};

    const long abase = b * strideA, bbase = b * strideB;
    unsigned short* AsW = &As[0][0] + ((tid >> 6) << 9);   // wave-uniform LDS base
    unsigned short* BsW = &Bs[0][0] + ((tid >> 6) << 9);

    for (int seg = 0; seg < NSEG; ++seg) {
        const unsigned short* Ap = (seg == 0) ? A0 : ((seg == 1) ? A1 : A2);
        const unsigned short* Bp = (seg == 0) ? B0 : ((seg == 1) ? B1 : B2);
        for (int k0 = 0; k0 < 256; k0 += 32) {
            if (MODE == 1) {
                __syncthreads();
#pragma unroll
                for (int r = 0; r < 2; ++r) {
                    const int row = lrow + (r << 6);
                    u16x8 av;
                    if (seg == 2) {
                        const long off = (long)(m0 + row) * lda + k0 + lkc;
                        u16x8 gv = *(const u16x8*)(A0 + off);
                        u16x8 cv = *(const u16x8*)(A1 + off);
#pragma unroll
                        for (int e = 0; e < 8; ++e)
                            av[e] = f2hu(hu2f(gv[e]) * hu2f(cv[e]));
                    } else {
                        av = *(const u16x8*)(Ap + (long)(m0 + row) * lda + k0 + lkc);
                    }
                    *(u16x8*)&As[row][lkc] = av;
                    u16x8 bv = *(const u16x8*)(Bp + (long)(n0 + row) * ldb + k0 + lkc);
                    *(u16x8*)&Bs[row][lkc] = bv;
                }
                __syncthreads();
            } else {
                const unsigned short* Abase = Ap + abase + (long)m0 * lda + k0;
                const unsigned short* Bbase = Bp + bbase + (long)n0 * ldb + k0;
                __syncthreads();
#pragma unroll
                for (int r = 0; r < 2; ++r) {
                    gl_lds16(Abase + (long)(lrow + (r << 6)) * lda + lkc, AsW + (r << 11));
                    gl_lds16(Bbase + (long)(lrow + (r << 6)) * ldb + lkc, BsW + (r << 11));
                }
                __syncthreads();
            }
            f16x8 af[4], bfv[4];
#pragma unroll
            for (int i = 0; i < 4; ++i) af[i]  = *(const f16x8*)&As[wm * 64 + i * 16 + frow][fk];
#pragma unroll
            for (int j = 0; j < 4; ++j) bfv[j] = *(const f16x8*)&Bs[wn * 64 + j * 16 + frow][fk];
#pragma unroll
            for (int i = 0; i < 4; ++i)
#pragma unroll
                for (int j = 0; j < 4; ++j)
                    acc[i][j] = __builtin_amdgcn_mfma_f32_16x16x32_f16(af[i], bfv[j], acc[i][j], 0, 0, 0);
        }
    }

    if (MODE == 0) {
        // S^T orientation: acc[ja][ib][e] = S[i = n0+wn*64+ib*16+(lane&15)]
        //                                    [j = m0+wm*64+ja*16+(lane>>4)*4+e]
        const int q = lane >> 4, c16 = lane & 15;
        // per-row(j) max over this wave's 64 i, then combine across wn
        float rm[4][4];
#pragma unroll
        for (int ja = 0; ja < 4; ++ja)
#pragma unroll
            for (int e = 0; e < 4; ++e) {
                float m = fmaxf(fmaxf(acc[ja][0][e], acc[ja][1][e]),
                                fmaxf(acc[ja][2][e], acc[ja][3][e]));
                m = fmaxf(m, __shfl_xor(m, 1));
                m = fmaxf(m, __shfl_xor(m, 2));
                m = fmaxf(m, __shfl_xor(m, 4));
                m = fmaxf(m, __shfl_xor(m, 8));
                rm[ja][e] = m;
            }
        if (c16 == 0) {
#pragma unroll
            for (int ja = 0; ja < 4; ++ja)
#pragma unroll
                for (int e = 0; e < 4; ++e)
                    smx[wn][wm * 64 + ja * 16 + q * 4 + e] = rm[ja][e];
        }
        __syncthreads();
        if (tid < 128) colm[tid] = fmaxf(smx[0][tid], smx[1][tid]);
        __syncthreads();
        // exp, z row-partials, tiled-fragment P' store
        unsigned short* Pt = Ch + b * strideC;
#pragma unroll
        for (int ja = 0; ja < 4; ++ja) {
            float mm[4];
#pragma unroll
            for (int e = 0; e < 4; ++e) mm[e] = colm[wm * 64 + ja * 16 + q * 4 + e];
            float zr[4] = {0.f, 0.f, 0.f, 0.f};
#pragma unroll
            for (int ib = 0; ib < 4; ++ib) {
                u16x4 pv;
#pragma unroll
                for (int e = 0; e < 4; ++e) {
                    float p = __expf(acc[ja][ib][e] - mm[e]);
                    zr[e] += p;
                    pv[e] = f2hu(p);
                }
                const long ti = (n0 >> 4) + wn * 4 + ib;
                const long tj = (m0 >> 4) + wm * 4 + ja;
                *(u16x4*)(Pt + (ti * (L / 16) + tj) * 256 + lane * 4) = pv;
            }
#pragma unroll
            for (int e = 0; e < 4; ++e) {
                float z = zr[e];
                z += __shfl_xor(z, 1); z += __shfl_xor(z, 2);
                z += __shfl_xor(z, 4); z += __shfl_xor(z, 8);
                if (c16 == 0) szx[wn][wm * 64 + ja * 16 + q * 4 + e] = z;
            }
        }
        __syncthreads();
        if (tid < 128) {
            const long o = ((long)b * NCH + blockIdx.y) * L + m0 + tid;
            pm[o] = colm[tid];
            pz[o] = szx[0][tid] + szx[1][tid];
        }
    } else {
#pragma unroll
        for (int i = 0; i < 4; ++i)
#pragma unroll
            for (int j = 0; j < 4; ++j) {
                const int rbase = m0 + wm * 64 + i * 16 + ((lane >> 4) << 2);
                const int col   = n0 + wn * 64 + j * 16 + frow;
                if (MODE == 2) {
#pragma unroll
                    for (int e = 0; e < 4; ++e)
                        Ch[(long)(rbase + e) * N + col] = f2hu(acc[i][j][e]);
                } else {
                    float* Cb = C + b * strideC;
                    const float bv = bias[col];
#pragma unroll
                    for (int e = 0; e < 4; ++e)
                        Cb[(long)(rbase + e) * N + col] = fmaxf(acc[i][j][e] + bv, 0.f);
                }
            }
    }
}

// ---------------------------------------------------------------------------
// attn v7: c[b,i,h] = sum_j (P'[i,j]*r[chunk,j]) * g[j,h]
// LDS-free, barrier-free: P' and gT pre-tiled in MFMA fragment layouts, so all
// loads are coalesced per-lane vector loads. 512 blocks x 4 waves; wave w owns
// h = w*64..+64, block owns 32 i rows; 64 independent j-window iterations.
// ---------------------------------------------------------------------------
__global__ __launch_bounds__(256)
void attn_av(const unsigned short* __restrict__ P, const unsigned short* __restrict__ r16,
             const unsigned short* __restrict__ gTf, unsigned short* __restrict__ ch)
{
    const int t = threadIdx.x, b = blockIdx.z;
    const int i0 = blockIdx.x * 32;
    const int w = t >> 6, l = t & 63, q = l >> 4, c16 = l & 15;
    const unsigned short* Pb0 = P + (long)b * LL + ((long)(i0 >> 4) * 128) * 256 + l * 4;
    const unsigned short* Pb1 = Pb0 + 128 * 256;
    const unsigned short* rb  = r16 + ((long)b * NCH + (i0 >> 7)) * L;
    const unsigned short* Bb0 = gTf + (long)b * LH + ((long)(w * 4) * 64) * 512 + l * 8;
    unsigned short* cb = ch + (long)b * LH;

    f32x4 acc[2][4];
#pragma unroll
    for (int i = 0; i < 2; ++i)
#pragma unroll
        for (int j = 0; j < 4; ++j) acc[i][j] = (f32x4){0.f, 0.f, 0.f, 0.f};

#pragma unroll 2
    for (int s = 0; s < 64; ++s) {
        union { u16x4 u[2]; f16x8 h; } a0v, a1v, rv;
        a0v.u[0] = *(const u16x4*)(Pb0 + (2 * s    ) * 256);
        a0v.u[1] = *(const u16x4*)(Pb0 + (2 * s + 1) * 256);
        a1v.u[0] = *(const u16x4*)(Pb1 + (2 * s    ) * 256);
        a1v.u[1] = *(const u16x4*)(Pb1 + (2 * s + 1) * 256);
        rv.u[0]  = *(const u16x4*)(rb + s * 32 + q * 4);
        rv.u[1]  = *(const u16x4*)(rb + s * 32 + 16 + q * 4);
        f16x8 a0 = a0v.h * rv.h;
        f16x8 a1 = a1v.h * rv.h;
#pragma unroll
        for (int j4 = 0; j4 < 4; ++j4) {
            u16x8 bu = *(const u16x8*)(Bb0 + ((long)j4 * 64 + s) * 512);
            f16x8 bf = *(f16x8*)&bu;
            acc[0][j4] = __builtin_amdgcn_mfma_f32_16x16x32_f16(a0, bf, acc[0][j4], 0, 0, 0);
            acc[1][j4] = __builtin_amdgcn_mfma_f32_16x16x32_f16(a1, bf, acc[1][j4], 0, 0, 0);
        }
    }

#pragma unroll
    for (int i = 0; i < 2; ++i)
#pragma unroll
        for (int j = 0; j < 4; ++j) {
            const int rbase = i0 + i * 16 + q * 4;
            const int col   = w * 64 + j * 16 + c16;
#pragma unroll
            for (int e = 0; e < 4; ++e)
                cb[(long)(rbase + e) * H + col] = f2hu(acc[i][j][e]);
        }
}

// ---------------------------------------------------------------------------
extern "C" void kernel_launch(void* const* d_in, const int* in_sizes, int n_in,
                              void* d_out, int out_size, void* d_ws, size_t ws_size,
                              hipStream_t stream)
{
    const float* g     = (const float*)d_in[0];
    const float* WP    = (const float*)d_in[1];
    const float* W_out = (const float*)d_in[2];
    const float* b_out = (const float*)d_in[3];
    float* out = (float*)d_out;

    // ---- workspace layout (bytes), total ~104 MB ----
    char* w = (char*)d_ws;
    unsigned short* P    = (unsigned short*)w;                  // 64 MB  P' tiled
    unsigned short* gh   = (unsigned short*)(w + 67108864);     // 8 MB
    unsigned short* ch   = (unsigned short*)(w + 75497472);     // 8 MB
    unsigned short* gTf  = (unsigned short*)(w + 83886080);     // 8 MB  gT frag-tiled
    unsigned short* Whh  = (unsigned short*)(w + 92274688);     // 8 MB
    unsigned short* WPh  = (unsigned short*)(w + 100663296);    // 128 KB
    unsigned short* Woh  = (unsigned short*)(w + 100794368);    // 384 KB
    float*          pm   = (float*)(w + 101187584);             // 1 MB
    float*          pz   = (float*)(w + 102236160);             // 1 MB
    unsigned short* r16  = (unsigned short*)(w + 103284736);    // 512 KB

    // 1) converts fp32 -> fp16
    cvt_g<<<dim3((int)(BL * H / 1024)), 256, 0, stream>>>(g, gh);
    cvt_two<<<dim3(256), 256, 0, stream>>>(WP, WPh, W_out, Woh);

    // 2) K1: Wh = g @ WP^T -> fp16 row-major
    mfma_nt<2, 1><<<dim3((int)(BL / 128), H / 128, 1), 256, 0, stream>>>(
        gh, nullptr, nullptr, WPh, nullptr, nullptr, nullptr, Whh,
        nullptr, nullptr, nullptr, H, H, H, 0, 0, 0);

    // 3) K2 (swapped): S^T tiles -> P' tiled frags + per-chunk row stats
    mfma_nt<0, 1><<<dim3(L / 128, L / 128, Bb), 256, 0, stream>>>(
        gh, nullptr, nullptr, Whh, nullptr, nullptr, nullptr, P,
        pm, pz, nullptr, L, H, H, LH, LH, LL);

    // 4) rescale factors r16 (fp16)
    col_stats_r<<<dim3((int)(BL / 256)), 256, 0, stream>>>(pm, pz, r16);

    // 5) transpose gh -> gTf (fragment-tiled)
    transpose_h16<<<dim3(L / 32, H / 32, Bb), 256, 0, stream>>>(gh, gTf);

    // 6) attn: c = (P' .* r) @ g -> ch (fp16)
    attn_av<<<dim3(L / 32, 1, Bb), 256, 0, stream>>>(P, r16, gTf, ch);

    // 7) K5: out = relu([g, c, g*c] @ W_out^T + b)
    mfma_nt<1, 3><<<dim3((int)(BL / 128), H / 128, 1), 256, 0, stream>>>(
        gh, ch, nullptr, Woh, Woh + 256, Woh + 512, out, nullptr,
        nullptr, nullptr, b_out, H, H, 3 * H, 0, 0, 0);
}

// Round 13
// 201.283 us; speedup vs baseline: 1.0017x; 1.0017x over previous
//
#include <hip/hip_runtime.h>
#include <math.h>

static constexpr int  Bb = 8;
static constexpr int  L  = 2048;
static constexpr int  H  = 256;
static constexpr long BL = (long)Bb * L;     // 16384
static constexpr long LH = (long)L * H;      // 524288
static constexpr long LL = (long)L * L;      // 4194304
static constexpr int  NCH = 16;              // i-chunks (128 each) for stats

typedef __attribute__((ext_vector_type(8))) unsigned short u16x8;
typedef __attribute__((ext_vector_type(4))) unsigned short u16x4;
typedef __attribute__((ext_vector_type(8))) _Float16       f16x8;
typedef __attribute__((ext_vector_type(4))) float          f32x4;

__device__ __forceinline__ unsigned short f2hu(float x) {
    union { _Float16 h; unsigned short u; } v; v.h = (_Float16)x; return v.u;
}
__device__ __forceinline__ float hu2f(unsigned short u) {
    union { unsigned short u; _Float16 h; } v; v.u = u; return (float)v.h;
}
__device__ __forceinline__ void gl_lds16(const unsigned short* g, unsigned short* l) {
    __builtin_amdgcn_global_load_lds(
        (const __attribute__((address_space(1))) unsigned int*)g,
        (__attribute__((address_space(3))) unsigned int*)l, 16, 0, 0);
}

// ---------------------------------------------------------------------------
// fused: g fp32 -> gh fp16 (row-major) + gTf (MFMA-B-fragment tiled)
// gTf[b][h/16][j/32][lane][8]; elem e at j = (e>>2)*16 + (lane>>4)*4 + (e&3)
// ---------------------------------------------------------------------------
__global__ __launch_bounds__(256)
void cvt_g_t(const float* __restrict__ g, unsigned short* __restrict__ gh,
             unsigned short* __restrict__ gTf)
{
    __shared__ unsigned short T[32][33];
    const int b = blockIdx.z, j0 = blockIdx.x * 32, h0 = blockIdx.y * 32;
    const int t = threadIdx.x, r = t >> 3, c4 = (t & 7) << 2;
    const long off = (long)b * LH + (long)(j0 + r) * H + h0 + c4;
    float4 v = *(const float4*)(g + off);
    u16x4 o;
    o[0] = f2hu(v.x); o[1] = f2hu(v.y); o[2] = f2hu(v.z); o[3] = f2hu(v.w);
    *(u16x4*)(gh + off) = o;
#pragma unroll
    for (int e = 0; e < 4; ++e) T[r][c4 + e] = o[e];
    __syncthreads();
    unsigned short* ob = gTf + (long)b * LH;
    const int f = t >> 7, lam = (t & 127) >> 1, half = t & 1;
    const int hloc  = f * 16 + (lam & 15);
    const int jbase = half * 16 + (lam >> 4) * 4;
    u16x4 w;
#pragma unroll
    for (int d = 0; d < 4; ++d) w[d] = T[jbase + d][hloc];
    *(u16x4*)(ob + ((long)((h0 >> 4) + f) * (L / 32) + (j0 >> 5)) * 512
                 + lam * 8 + half * 4) = w;
}

// WP (blocks [0,64)) + W_out (blocks [64,256)) in one launch
__global__ __launch_bounds__(256)
void cvt_two(const float* __restrict__ x1, unsigned short* __restrict__ h1,
             const float* __restrict__ x2, unsigned short* __restrict__ h2)
{
    const float* x; unsigned short* hp; long base;
    if (blockIdx.x < 64) { x = x1; hp = h1; base = (long)blockIdx.x * 1024; }
    else { x = x2; hp = h2; base = (long)(blockIdx.x - 64) * 1024; }
    const long i = base + (long)threadIdx.x * 4;
    float4 v = *(const float4*)(x + i);
    u16x4 o;
    o[0] = f2hu(v.x); o[1] = f2hu(v.y); o[2] = f2hu(v.z); o[3] = f2hu(v.w);
    *(u16x4*)(hp + i) = o;
}

// ---------------------------------------------------------------------------
// combine per-chunk stats -> fp16 rescale factors r16[b][c][j] = exp(m_c-m)*zi
// ---------------------------------------------------------------------------
__global__ __launch_bounds__(256)
void col_stats_r(const float* __restrict__ pm, const float* __restrict__ pz,
                 unsigned short* __restrict__ r16)
{
    const long idx = (long)blockIdx.x * 256 + threadIdx.x;   // b*L + j
    const long b = idx / L, j = idx - b * L;
    const float* pmb = pm + b * (long)NCH * L + j;
    const float* pzb = pz + b * (long)NCH * L + j;
    float m = -1e30f;
#pragma unroll
    for (int c = 0; c < NCH; ++c) m = fmaxf(m, pmb[(long)c * L]);
    float z = 0.f;
#pragma unroll
    for (int c = 0; c < NCH; ++c) z += pzb[(long)c * L] * __expf(pmb[(long)c * L] - m);
    const float zi = 1.f / z;
    unsigned short* rb = r16 + b * (long)NCH * L + j;
#pragma unroll
    for (int c = 0; c < NCH; ++c) rb[(long)c * L] = f2hu(__expf(pmb[(long)c * L] - m) * zi);
}

// ---------------------------------------------------------------------------
// Unified NT MFMA GEMM (fp16 inputs), 128x128 tile, BK=32.
// MODE 0 (K2, swapped A=g/B=Wh => S^T tiles): 2-phase double-buffered pipeline
//   (stage next while MFMA current; counted vmcnt + raw s_barrier), then
//   row-stats + P' = fp16(exp(s - m_chunk)) in A-frag tiled layout.
// MODE 2 (K1): same 2-phase loop, plain fp16 C write.
// MODE 1 (K5): seg2 A synthesized fp16(A0*A1), bias+relu; reg-staged, K=768.
// ---------------------------------------------------------------------------
template<int MODE, int NSEG>
__global__ __launch_bounds__(256)
void mfma_nt(const unsigned short* A0, const unsigned short* A1, const unsigned short* A2,
             const unsigned short* B0, const unsigned short* B1, const unsigned short* B2,
             float* __restrict__ C, unsigned short* __restrict__ Ch,
             float* __restrict__ pm, float* __restrict__ pz,
             const float* __restrict__ bias,
             int N, int lda, int ldb,
             long strideA, long strideB, long strideC)
{
    constexpr int DB = (MODE == 1) ? 1 : 2;
    __shared__ __align__(16) unsigned short As[DB][128][32];
    __shared__ __align__(16) unsigned short Bs[DB][128][32];
    __shared__ float smx[2][128];
    __shared__ float szx[2][128];
    __shared__ float colm[128];
    const int tid  = threadIdx.x;
    const int wid  = tid >> 6, lane = tid & 63;
    const int wm   = wid >> 1, wn = wid & 1;
    const long b   = blockIdx.z;
    const int m0   = blockIdx.x * 128, n0 = blockIdx.y * 128;
    const int lrow = tid >> 2, lkc = (tid & 3) << 3;
    const int frow = lane & 15, fk = (lane >> 4) << 3;
    f32x4 acc[4][4];
#pragma unroll
    for (int i = 0; i < 4; ++i)
#pragma unroll
        for (int j = 0; j < 4; ++j) acc[i][j] = (f32x4){0.f, 0.f, 0.f, 0.f};

    const long abase = b * strideA, bbase = b * strideB;

    if (MODE == 1) {
        for (int seg = 0; seg < NSEG; ++seg) {
            const unsigned short* Ap = (seg == 0) ? A0 : ((seg == 1) ? A1 : A2);
            const unsigned short* Bp = (seg == 0) ? B0 : ((seg == 1) ? B1 : B2);
            for (int k0 = 0; k0 < 256; k0 += 32) {
                __syncthreads();
#pragma unroll
                for (int r = 0; r < 2; ++r) {
                    const int row = lrow + (r << 6);
                    u16x8 av;
                    if (seg == 2) {
                        const long off = (long)(m0 + row) * lda + k0 + lkc;
                        u16x8 gv = *(const u16x8*)(A0 + off);
                        u16x8 cv = *(const u16x8*)(A1 + off);
#pragma unroll
                        for (int e = 0; e < 8; ++e)
                            av[e] = f2hu(hu2f(gv[e]) * hu2f(cv[e]));
                    } else {
                        av = *(const u16x8*)(Ap + (long)(m0 + row) * lda + k0 + lkc);
                    }
                    *(u16x8*)&As[0][row][lkc] = av;
                    u16x8 bv = *(const u16x8*)(Bp + (long)(n0 + row) * ldb + k0 + lkc);
                    *(u16x8*)&Bs[0][row][lkc] = bv;
                }
                __syncthreads();
                f16x8 af[4], bfv[4];
#pragma unroll
                for (int i = 0; i < 4; ++i) af[i]  = *(const f16x8*)&As[0][wm * 64 + i * 16 + frow][fk];
#pragma unroll
                for (int j = 0; j < 4; ++j) bfv[j] = *(const f16x8*)&Bs[0][wn * 64 + j * 16 + frow][fk];
#pragma unroll
                for (int i = 0; i < 4; ++i)
#pragma unroll
                    for (int j = 0; j < 4; ++j)
                        acc[i][j] = __builtin_amdgcn_mfma_f32_16x16x32_f16(af[i], bfv[j], acc[i][j], 0, 0, 0);
            }
        }
    } else {
        // ---- 2-phase pipelined K=256 loop ----
        const unsigned short* Abase = A0 + abase + (long)m0 * lda;
        const unsigned short* Bbase = B0 + bbase + (long)n0 * ldb;
        unsigned short* AsW = &As[0][0][0] + ((tid >> 6) << 9);   // wave-uniform
        unsigned short* BsW = &Bs[0][0][0] + ((tid >> 6) << 9);

#define STG(BUF, KO)                                                         \
        {                                                                    \
            _Pragma("unroll")                                                \
            for (int r = 0; r < 2; ++r) {                                    \
                gl_lds16(Abase + (long)(lrow + (r << 6)) * lda + (KO) + lkc, \
                         AsW + (BUF) * 4096 + (r << 11));                    \
                gl_lds16(Bbase + (long)(lrow + (r << 6)) * ldb + (KO) + lkc, \
                         BsW + (BUF) * 4096 + (r << 11));                    \
            }                                                                \
        }

        STG(0, 0)
        asm volatile("s_waitcnt vmcnt(0)" ::: "memory");
        __builtin_amdgcn_s_barrier();
        __builtin_amdgcn_sched_barrier(0);

#pragma unroll
        for (int ks = 0; ks < 8; ++ks) {
            const int cur = ks & 1;
            if (ks < 7) STG(cur ^ 1, (ks + 1) * 32)
            f16x8 af[4], bfv[4];
#pragma unroll
            for (int i = 0; i < 4; ++i) af[i]  = *(const f16x8*)&As[cur][wm * 64 + i * 16 + frow][fk];
#pragma unroll
            for (int j = 0; j < 4; ++j) bfv[j] = *(const f16x8*)&Bs[cur][wn * 64 + j * 16 + frow][fk];
#pragma unroll
            for (int i = 0; i < 4; ++i)
#pragma unroll
                for (int j = 0; j < 4; ++j)
                    acc[i][j] = __builtin_amdgcn_mfma_f32_16x16x32_f16(af[i], bfv[j], acc[i][j], 0, 0, 0);
            if (ks < 7) { asm volatile("s_waitcnt vmcnt(0)" ::: "memory"); }
            __builtin_amdgcn_s_barrier();
            __builtin_amdgcn_sched_barrier(0);
        }
#undef STG
    }

    if (MODE == 0) {
        // S^T orientation: acc[ja][ib][e] = S[i = n0+wn*64+ib*16+(lane&15)]
        //                                    [j = m0+wm*64+ja*16+(lane>>4)*4+e]
        const int q = lane >> 4, c16 = lane & 15;
        float rm[4][4];
#pragma unroll
        for (int ja = 0; ja < 4; ++ja)
#pragma unroll
            for (int e = 0; e < 4; ++e) {
                float m = fmaxf(fmaxf(acc[ja][0][e], acc[ja][1][e]),
                                fmaxf(acc[ja][2][e], acc[ja][3][e]));
                m = fmaxf(m, __shfl_xor(m, 1));
                m = fmaxf(m, __shfl_xor(m, 2));
                m = fmaxf(m, __shfl_xor(m, 4));
                m = fmaxf(m, __shfl_xor(m, 8));
                rm[ja][e] = m;
            }
        if (c16 == 0) {
#pragma unroll
            for (int ja = 0; ja < 4; ++ja)
#pragma unroll
                for (int e = 0; e < 4; ++e)
                    smx[wn][wm * 64 + ja * 16 + q * 4 + e] = rm[ja][e];
        }
        __syncthreads();
        if (tid < 128) colm[tid] = fmaxf(smx[0][tid], smx[1][tid]);
        __syncthreads();
        unsigned short* Pt = Ch + b * strideC;
#pragma unroll
        for (int ja = 0; ja < 4; ++ja) {
            float mm[4];
#pragma unroll
            for (int e = 0; e < 4; ++e) mm[e] = colm[wm * 64 + ja * 16 + q * 4 + e];
            float zr[4] = {0.f, 0.f, 0.f, 0.f};
#pragma unroll
            for (int ib = 0; ib < 4; ++ib) {
                u16x4 pv;
#pragma unroll
                for (int e = 0; e < 4; ++e) {
                    float p = __expf(acc[ja][ib][e] - mm[e]);
                    zr[e] += p;
                    pv[e] = f2hu(p);
                }
                const long ti = (n0 >> 4) + wn * 4 + ib;
                const long tj = (m0 >> 4) + wm * 4 + ja;
                *(u16x4*)(Pt + (ti * (L / 16) + tj) * 256 + lane * 4) = pv;
            }
#pragma unroll
            for (int e = 0; e < 4; ++e) {
                float z = zr[e];
                z += __shfl_xor(z, 1); z += __shfl_xor(z, 2);
                z += __shfl_xor(z, 4); z += __shfl_xor(z, 8);
                if (c16 == 0) szx[wn][wm * 64 + ja * 16 + q * 4 + e] = z;
            }
        }
        __syncthreads();
        if (tid < 128) {
            const long o = ((long)b * NCH + blockIdx.y) * L + m0 + tid;
            pm[o] = colm[tid];
            pz[o] = szx[0][tid] + szx[1][tid];
        }
    } else {
#pragma unroll
        for (int i = 0; i < 4; ++i)
#pragma unroll
            for (int j = 0; j < 4; ++j) {
                const int rbase = m0 + wm * 64 + i * 16 + ((lane >> 4) << 2);
                const int col   = n0 + wn * 64 + j * 16 + frow;
                if (MODE == 2) {
#pragma unroll
                    for (int e = 0; e < 4; ++e)
                        Ch[(long)(rbase + e) * N + col] = f2hu(acc[i][j][e]);
                } else {
                    float* Cb = C + b * strideC;
                    const float bv = bias[col];
#pragma unroll
                    for (int e = 0; e < 4; ++e)
                        Cb[(long)(rbase + e) * N + col] = fmaxf(acc[i][j][e] + bv, 0.f);
                }
            }
    }
}

// ---------------------------------------------------------------------------
// attn v7: c[b,i,h] = sum_j (P'[i,j]*r[chunk,j]) * g[j,h]
// LDS-free, barrier-free: P' and gT pre-tiled in MFMA fragment layouts.
// 512 blocks x 4 waves; wave w owns h=w*64..+64; block owns 32 i rows.
// ---------------------------------------------------------------------------
__global__ __launch_bounds__(256)
void attn_av(const unsigned short* __restrict__ P, const unsigned short* __restrict__ r16,
             const unsigned short* __restrict__ gTf, unsigned short* __restrict__ ch)
{
    const int t = threadIdx.x, b = blockIdx.z;
    const int i0 = blockIdx.x * 32;
    const int w = t >> 6, l = t & 63, q = l >> 4, c16 = l & 15;
    const unsigned short* Pb0 = P + (long)b * LL + ((long)(i0 >> 4) * 128) * 256 + l * 4;
    const unsigned short* Pb1 = Pb0 + 128 * 256;
    const unsigned short* rb  = r16 + ((long)b * NCH + (i0 >> 7)) * L;
    const unsigned short* Bb0 = gTf + (long)b * LH + ((long)(w * 4) * 64) * 512 + l * 8;
    unsigned short* cb = ch + (long)b * LH;

    f32x4 acc[2][4];
#pragma unroll
    for (int i = 0; i < 2; ++i)
#pragma unroll
        for (int j = 0; j < 4; ++j) acc[i][j] = (f32x4){0.f, 0.f, 0.f, 0.f};

#pragma unroll 2
    for (int s = 0; s < 64; ++s) {
        union { u16x4 u[2]; f16x8 h; } a0v, a1v, rv;
        a0v.u[0] = *(const u16x4*)(Pb0 + (2 * s    ) * 256);
        a0v.u[1] = *(const u16x4*)(Pb0 + (2 * s + 1) * 256);
        a1v.u[0] = *(const u16x4*)(Pb1 + (2 * s    ) * 256);
        a1v.u[1] = *(const u16x4*)(Pb1 + (2 * s + 1) * 256);
        rv.u[0]  = *(const u16x4*)(rb + s * 32 + q * 4);
        rv.u[1]  = *(const u16x4*)(rb + s * 32 + 16 + q * 4);
        f16x8 a0 = a0v.h * rv.h;
        f16x8 a1 = a1v.h * rv.h;
#pragma unroll
        for (int j4 = 0; j4 < 4; ++j4) {
            u16x8 bu = *(const u16x8*)(Bb0 + ((long)j4 * 64 + s) * 512);
            f16x8 bf = *(f16x8*)&bu;
            acc[0][j4] = __builtin_amdgcn_mfma_f32_16x16x32_f16(a0, bf, acc[0][j4], 0, 0, 0);
            acc[1][j4] = __builtin_amdgcn_mfma_f32_16x16x32_f16(a1, bf, acc[1][j4], 0, 0, 0);
        }
    }

#pragma unroll
    for (int i = 0; i < 2; ++i)
#pragma unroll
        for (int j = 0; j < 4; ++j) {
            const int rbase = i0 + i * 16 + q * 4;
            const int col   = w * 64 + j * 16 + c16;
#pragma unroll
            for (int e = 0; e < 4; ++e)
                cb[(long)(rbase + e) * H + col] = f2hu(acc[i][j][e]);
        }
}

// ---------------------------------------------------------------------------
extern "C" void kernel_launch(void* const* d_in, const int* in_sizes, int n_in,
                              void* d_out, int out_size, void* d_ws, size_t ws_size,
                              hipStream_t stream)
{
    const float* g     = (const float*)d_in[0];
    const float* WP    = (const float*)d_in[1];
    const float* W_out = (const float*)d_in[2];
    const float* b_out = (const float*)d_in[3];
    float* out = (float*)d_out;

    // ---- workspace layout (bytes), total ~104 MB ----
    char* w = (char*)d_ws;
    unsigned short* P    = (unsigned short*)w;                  // 64 MB  P' tiled
    unsigned short* gh   = (unsigned short*)(w + 67108864);     // 8 MB
    unsigned short* ch   = (unsigned short*)(w + 75497472);     // 8 MB
    unsigned short* gTf  = (unsigned short*)(w + 83886080);     // 8 MB  gT frag-tiled
    unsigned short* Whh  = (unsigned short*)(w + 92274688);     // 8 MB
    unsigned short* WPh  = (unsigned short*)(w + 100663296);    // 128 KB
    unsigned short* Woh  = (unsigned short*)(w + 100794368);    // 384 KB
    float*          pm   = (float*)(w + 101187584);             // 1 MB
    float*          pz   = (float*)(w + 102236160);             // 1 MB
    unsigned short* r16  = (unsigned short*)(w + 103284736);    // 512 KB

    // 1) converts: g -> gh + gTf (fused); weights
    cvt_g_t<<<dim3(L / 32, H / 32, Bb), 256, 0, stream>>>(g, gh, gTf);
    cvt_two<<<dim3(256), 256, 0, stream>>>(WP, WPh, W_out, Woh);

    // 2) K1: Wh = g @ WP^T -> fp16 row-major (2-phase pipelined)
    mfma_nt<2, 1><<<dim3((int)(BL / 128), H / 128, 1), 256, 0, stream>>>(
        gh, nullptr, nullptr, WPh, nullptr, nullptr, nullptr, Whh,
        nullptr, nullptr, nullptr, H, H, H, 0, 0, 0);

    // 3) K2 (swapped): S^T tiles -> P' tiled frags + per-chunk row stats
    mfma_nt<0, 1><<<dim3(L / 128, L / 128, Bb), 256, 0, stream>>>(
        gh, nullptr, nullptr, Whh, nullptr, nullptr, nullptr, P,
        pm, pz, nullptr, L, H, H, LH, LH, LL);

    // 4) rescale factors r16 (fp16)
    col_stats_r<<<dim3((int)(BL / 256)), 256, 0, stream>>>(pm, pz, r16);

    // 5) attn: c = (P' .* r) @ g -> ch (fp16)
    attn_av<<<dim3(L / 32, 1, Bb), 256, 0, stream>>>(P, r16, gTf, ch);

    // 6) K5: out = relu([g, c, g*c] @ W_out^T + b)
    mfma_nt<1, 3><<<dim3((int)(BL / 128), H / 128, 1), 256, 0, stream>>>(
        gh, ch, nullptr, Woh, Woh + 256, Woh + 512, out, nullptr,
        nullptr, nullptr, b_out, H, H, 3 * H, 0, 0, 0);
}